// Round 5
// baseline (91.814 us; speedup 1.0000x reference)
//
#include <hip/hip_runtime.h>
#include <math.h>

// ---- DCT constants (fp32) ----
#define A0c 0.35355339059327373f
#define C1c 0.4903926402016152f
#define C2c 0.46193976625564337f
#define C3c 0.41573480615127262f
#define C5c 0.27778511650980114f
#define C6c 0.19134171618254492f
#define C7c 0.09754516100806417f

#define IMG_W 512
#define IMG_HW (512 * 512)

typedef _Float16 half8v __attribute__((ext_vector_type(8)));
typedef float f8v __attribute__((ext_vector_type(8)));

// In-place 8-point DCT-II (rows of D = 0.5*c(u)*cos((2x+1)u*pi/16))
__device__ __forceinline__ void fdct8(float v[8]) {
    float s0 = v[0] + v[7], s1 = v[1] + v[6], s2 = v[2] + v[5], s3 = v[3] + v[4];
    float d0 = v[0] - v[7], d1 = v[1] - v[6], d2 = v[2] - v[5], d3 = v[3] - v[4];
    float e0 = s0 + s3, e1 = s1 + s2, f0 = s0 - s3, f1 = s1 - s2;
    v[0] = A0c * (e0 + e1);
    v[4] = A0c * (e0 - e1);
    v[2] = C2c * f0 + C6c * f1;
    v[6] = C6c * f0 - C2c * f1;
    v[1] = C1c * d0 + C3c * d1 + C5c * d2 + C7c * d3;
    v[3] = C3c * d0 - C7c * d1 - C1c * d2 - C5c * d3;
    v[5] = C5c * d0 - C1c * d1 + C7c * d2 + C3c * d3;
    v[7] = C7c * d0 - C5c * d1 + C3c * d2 - C1c * d3;
}

// In-place 8-point inverse: x[n] = sum_u D[u][n] c[u]
__device__ __forceinline__ void idct8(float v[8]) {
    float g0 = v[0], g1 = v[1], g2 = v[2], g3 = v[3];
    float g4 = v[4], g5 = v[5], g6 = v[6], g7 = v[7];
    float ep = A0c * (g0 + g4), em = A0c * (g0 - g4);
    float t26a = C2c * g2 + C6c * g6;
    float t26b = C6c * g2 - C2c * g6;
    float e0 = ep + t26a;
    float e1 = em + t26b;
    float e2 = em - t26b;
    float e3 = ep - t26a;
    float o0 = C1c * g1 + C3c * g3 + C5c * g5 + C7c * g7;
    float o1 = C3c * g1 - C7c * g3 - C1c * g5 - C5c * g7;
    float o2 = C5c * g1 - C1c * g3 + C7c * g5 + C3c * g7;
    float o3 = C7c * g1 - C5c * g3 + C3c * g5 - C1c * g7;
    v[0] = e0 + o0; v[7] = e0 - o0;
    v[1] = e1 + o1; v[6] = e1 - o1;
    v[2] = e2 + o2; v[5] = e2 - o2;
    v[3] = e3 + o3; v[4] = e3 - o3;
}

// soft quantize-dequantize: d = x/q; sr = d + 0.5*tanh(15*(d - round(d))); return sr*q
__device__ __forceinline__ float softq(float x, float q, float rq) {
    float d = x * rq;
    float rn = rintf(d);                   // nearest-even, matches jnp.round
    float t = d - rn;                      // in [-0.5, 0.5]
    float e = __expf(-30.0f * fabsf(t));   // tanh(15t) via exp
    float th = (1.0f - e) * __builtin_amdgcn_rcpf(1.0f + e);
    th = copysignf(th, t);
    return (d + 0.5f * th) * q;
}

template <int CH>
__device__ __forceinline__ void quant_block(float X[8][8]) {
    static constexpr float QL[64] = {
        16,11,10,16,24,40,51,61,  12,12,14,19,26,58,60,55,
        14,13,16,24,40,57,69,56,  14,17,22,29,51,87,80,62,
        18,22,37,56,68,109,103,77, 24,35,55,64,81,104,113,92,
        49,64,78,87,103,121,120,101, 72,92,95,98,112,100,103,99};
    static constexpr float QC[64] = {
        17,18,24,47,99,99,99,99,  18,21,26,66,99,99,99,99,
        24,26,56,99,99,99,99,99,  47,66,99,99,99,99,99,99,
        99,99,99,99,99,99,99,99,  99,99,99,99,99,99,99,99,
        99,99,99,99,99,99,99,99,  99,99,99,99,99,99,99,99};
#pragma unroll
    for (int u = 0; u < 8; ++u) {
#pragma unroll
        for (int v = 0; v < 8; ++v) {
            float q = (CH == 0) ? QL[u * 8 + v] : QC[u * 8 + v];
            float rq = (CH == 0) ? (1.0f / QL[u * 8 + v]) : (1.0f / QC[u * 8 + v]);
            X[u][v] = softq(X[u][v], q, rq);
        }
    }
}

// Block = 192 threads = 3 waves, one wave per channel in the transform (no
// idle lanes). No min-waves launch bound (R2 lesson: forcing it spills).
// Direct global->register loads (no staging phase): for fixed row, the 64
// lanes of a wave read 64 contiguous 32B chunks = one coalesced 2KB request.
// The 3 waves re-read each other's channels through L1/L2 (same 48KB strip,
// same CU) - HBM fetch unaffected.
__global__ __launch_bounds__(192) void jpeg_kernel(const float* __restrict__ x,
                                                   float* __restrict__ out) {
    // fp16 exchange for reconstructed Y/Cb/Cr: [ch][row][col], 24 KB.
    __shared__ _Float16 ldsH[3 * 8 * 512];

    const int tid = threadIdx.x;
    const int s = blockIdx.x;
    const int b = s >> 6;     // batch
    const int gh = s & 63;    // 8-row strip index

    const float* xb = x + (size_t)b * 3 * IMG_HW + (size_t)gh * 8 * IMG_W;
    float* ob = out + (size_t)b * 3 * IMG_HW + (size_t)gh * 8 * IMG_W;

    // ---------- phase B: direct load + forward color + transform ----------
    {
        const int ch = tid >> 6;    // wave index = output channel
        const int blk = tid & 63;   // lane = 8x8 block within the strip

        // wave-uniform forward color weights
        float w0, w1, w2, woff;
        if (ch == 0)      { w0 = 0.299f;     w1 = 0.587f;     w2 = 0.114f;     woff = -0.5f; }
        else if (ch == 1) { w0 = -0.168736f; w1 = -0.331264f; w2 = 0.5f;       woff = 0.0f;  }
        else              { w0 = 0.5f;       w1 = -0.418688f; w2 = -0.081312f; woff = 0.0f;  }

        const float* pr = xb + blk * 8;
        const float* pg = pr + IMG_HW;
        const float* pb = pg + IMG_HW;

        float X[8][8];
#pragma unroll
        for (int r = 0; r < 8; ++r) {
            f8v rv = *(const f8v*)(pr + r * IMG_W);
            f8v gv = *(const f8v*)(pg + r * IMG_W);
            f8v bv = *(const f8v*)(pb + r * IMG_W);
#pragma unroll
            for (int k = 0; k < 8; ++k)
                X[r][k] = w0 * rv[k] + w1 * gv[k] + w2 * bv[k] + woff;
            // fuse the row DCT immediately: shortens live ranges of rv/gv/bv
            fdct8(X[r]);
        }
        // columns
#pragma unroll
        for (int v = 0; v < 8; ++v) {
            float t[8];
#pragma unroll
            for (int u = 0; u < 8; ++u) t[u] = X[u][v];
            fdct8(t);
#pragma unroll
            for (int u = 0; u < 8; ++u) X[u][v] = t[u];
        }
        if (ch == 0) quant_block<0>(X); else quant_block<1>(X);
        // inverse: columns, then rows (row idct fused with fp16 convert+store)
#pragma unroll
        for (int v = 0; v < 8; ++v) {
            float t[8];
#pragma unroll
            for (int u = 0; u < 8; ++u) t[u] = X[u][v];
            idct8(t);
#pragma unroll
            for (int u = 0; u < 8; ++u) X[u][v] = t[u];
        }
#pragma unroll
        for (int r = 0; r < 8; ++r) {
            idct8(X[r]);
            half8v h;
#pragma unroll
            for (int k = 0; k < 8; ++k) h[k] = (_Float16)X[r][k];
            *(half8v*)&ldsH[ch * 4096 + r * 512 + blk * 8] = h;
        }
    }
    __syncthreads();

    // ---------- phase C: inverse color + coalesced store ----------
#pragma unroll
    for (int i = 0; i < 3; ++i) {
        int g = i * 192 + tid;        // 0..575; 512 groups of 8 px
        if (g < 512) {
            int r = g >> 6;               // 0..7
            int col8 = (g & 63) << 3;     // 0..504
            half8v hy  = *(half8v*)&ldsH[0 * 4096 + r * 512 + col8];
            half8v hcb = *(half8v*)&ldsH[1 * 4096 + r * 512 + col8];
            half8v hcr = *(half8v*)&ldsH[2 * 4096 + r * 512 + col8];
            f8v R, G, B;
#pragma unroll
            for (int k = 0; k < 8; ++k) {
                float Y  = (float)hy[k] + 0.5f;
                float Cb = (float)hcb[k];
                float Cr = (float)hcr[k];
                float Rv = Y + 1.402f * Cr;
                float Gv = Y - 0.344136f * Cb - 0.714136f * Cr;
                float Bv = Y + 1.772f * Cb;
                R[k] = fminf(fmaxf(Rv, 0.0f), 1.0f);
                G[k] = fminf(fmaxf(Gv, 0.0f), 1.0f);
                B[k] = fminf(fmaxf(Bv, 0.0f), 1.0f);
            }
            float* o0 = ob + r * IMG_W + col8;
            *(f8v*)(o0) = R;
            *(f8v*)(o0 + IMG_HW) = G;
            *(f8v*)(o0 + 2 * IMG_HW) = B;
        }
    }
}

extern "C" void kernel_launch(void* const* d_in, const int* in_sizes, int n_in,
                              void* d_out, int out_size, void* d_ws, size_t ws_size,
                              hipStream_t stream) {
    const float* x = (const float*)d_in[0];
    float* out = (float*)d_out;
    const int B = in_sizes[0] / (3 * IMG_HW);   // 32
    const int n_wg = B * 64;                    // one WG per (batch, 8-row strip)
    hipLaunchKernelGGL(jpeg_kernel, dim3(n_wg), dim3(192), 0, stream, x, out);
}

// Round 6
// 39.138 us; speedup vs baseline: 2.3459x; 2.3459x over previous
//
#include <hip/hip_runtime.h>
#include <math.h>

// ---- DCT constants (fp32) ----
#define A0c 0.35355339059327373f
#define C1c 0.4903926402016152f
#define C2c 0.46193976625564337f
#define C3c 0.41573480615127262f
#define C5c 0.27778511650980114f
#define C6c 0.19134171618254492f
#define C7c 0.09754516100806417f

#define IMG_W 512
#define IMG_HW (512 * 512)

typedef float f8v __attribute__((ext_vector_type(8)));

// base JPEG tables (QUALITY=50 -> scaled table == base table exactly)
__device__ const float QLUM[64] = {
    16,11,10,16,24,40,51,61,  12,12,14,19,26,58,60,55,
    14,13,16,24,40,57,69,56,  14,17,22,29,51,87,80,62,
    18,22,37,56,68,109,103,77, 24,35,55,64,81,104,113,92,
    49,64,78,87,103,121,120,101, 72,92,95,98,112,100,103,99};
__device__ const float QCHR[64] = {
    17,18,24,47,99,99,99,99,  18,21,26,66,99,99,99,99,
    24,26,56,99,99,99,99,99,  47,66,99,99,99,99,99,99,
    99,99,99,99,99,99,99,99,  99,99,99,99,99,99,99,99,
    99,99,99,99,99,99,99,99,  99,99,99,99,99,99,99,99};

// In-place 8-point DCT-II (rows of D = 0.5*c(u)*cos((2x+1)u*pi/16))
__device__ __forceinline__ void fdct8(float v[8]) {
    float s0 = v[0] + v[7], s1 = v[1] + v[6], s2 = v[2] + v[5], s3 = v[3] + v[4];
    float d0 = v[0] - v[7], d1 = v[1] - v[6], d2 = v[2] - v[5], d3 = v[3] - v[4];
    float e0 = s0 + s3, e1 = s1 + s2, f0 = s0 - s3, f1 = s1 - s2;
    v[0] = A0c * (e0 + e1);
    v[4] = A0c * (e0 - e1);
    v[2] = C2c * f0 + C6c * f1;
    v[6] = C6c * f0 - C2c * f1;
    v[1] = C1c * d0 + C3c * d1 + C5c * d2 + C7c * d3;
    v[3] = C3c * d0 - C7c * d1 - C1c * d2 - C5c * d3;
    v[5] = C5c * d0 - C1c * d1 + C7c * d2 + C3c * d3;
    v[7] = C7c * d0 - C5c * d1 + C3c * d2 - C1c * d3;
}

// In-place 8-point inverse: x[n] = sum_u D[u][n] c[u]
__device__ __forceinline__ void idct8(float v[8]) {
    float g0 = v[0], g1 = v[1], g2 = v[2], g3 = v[3];
    float g4 = v[4], g5 = v[5], g6 = v[6], g7 = v[7];
    float ep = A0c * (g0 + g4), em = A0c * (g0 - g4);
    float t26a = C2c * g2 + C6c * g6;
    float t26b = C6c * g2 - C2c * g6;
    float e0 = ep + t26a, e1 = em + t26b, e2 = em - t26b, e3 = ep - t26a;
    float o0 = C1c * g1 + C3c * g3 + C5c * g5 + C7c * g7;
    float o1 = C3c * g1 - C7c * g3 - C1c * g5 - C5c * g7;
    float o2 = C5c * g1 - C1c * g3 + C7c * g5 + C3c * g7;
    float o3 = C7c * g1 - C5c * g3 + C3c * g5 - C1c * g7;
    v[0] = e0 + o0; v[7] = e0 - o0;
    v[1] = e1 + o1; v[6] = e1 - o1;
    v[2] = e2 + o2; v[5] = e2 - o2;
    v[3] = e3 + o3; v[4] = e3 - o3;
}

// soft quantize-dequantize
__device__ __forceinline__ float softq(float x, float q, float rq) {
    float d = x * rq;
    float rn = rintf(d);                   // nearest-even, matches jnp.round
    float t = d - rn;                      // in [-0.5, 0.5]
    float e = __expf(-30.0f * fabsf(t));   // tanh(15t) via exp
    float th = (1.0f - e) * __builtin_amdgcn_rcpf(1.0f + e);
    th = copysignf(th, t);
    return (d + 0.5f * th) * q;
}

// One wave = one 64-col x 8-row tile, all 3 channels. Lane = (row<3b> , blk<3b>):
// lane holds an 8-px row-fragment (row `row` of block `blk`). NO __syncthreads
// anywhere: the only LDS exchange is the 8x8 transpose between the two 1-D DCT
// passes, and it is wave-private (in-order LDS within a wave).
// xpose layout slot(v, b, x) = v*72 + b*9 + x : both write patterns (fixed-v,
// addr=9b+x) and read patterns (fixed-k, addr=72j+9b+k) are conflict-free per
// 16-lane phase (9-word block skew).
__global__ __launch_bounds__(256) void jpeg_kernel(const float* __restrict__ x,
                                                   float* __restrict__ out) {
    __shared__ float xpose[4][576];   // per-wave transpose scratch (2304 B each)
    __shared__ float qt[2][64];       // transposed q tables: qt[t][v*8+u] = Q[u][v]

    const int tid = threadIdx.x;
    const int wid = tid >> 6;
    const int lane = tid & 63;

    // q-table init: every wave duplicate-writes identical values, then reads
    // its own writes later in program order -> no barrier needed.
    {
        int u = lane & 7, v = lane >> 3;
        qt[0][lane] = QLUM[u * 8 + v];
        qt[1][lane] = QCHR[u * 8 + v];
    }

    const int gw = blockIdx.x * 4 + wid;     // global wave id, 0..B*512-1
    const int bimg = gw >> 9;                // image (512 waves per image)
    const int rem = gw & 511;
    const int gh = rem >> 3;                 // 8-row strip index (0..63)
    const int tx = rem & 7;                  // 64-col tile index (0..7)

    const int blk = lane & 7;                // block within tile
    const int row = lane >> 3;               // row within strip (spatial x) / freq v

    const float* base = x + (size_t)bimg * 3 * IMG_HW +
                        (size_t)(gh * 8 + row) * IMG_W + tx * 64 + blk * 8;
    float* obase = out + (size_t)bimg * 3 * IMG_HW +
                   (size_t)(gh * 8 + row) * IMG_W + tx * 64 + blk * 8;

    // coalesced 32B loads (16-lane phase = 2 rows x 256B contiguous)
    const f8v Rv = *(const f8v*)(base);
    const f8v Gv = *(const f8v*)(base + IMG_HW);
    const f8v Bv = *(const f8v*)(base + 2 * IMG_HW);

    float* xp = xpose[wid];
    float rec[3][8];   // reconstructed row-fragments per channel

#pragma unroll
    for (int ch = 0; ch < 3; ++ch) {
        // ---- forward color for this channel (row fragment, in regs) ----
        float g[8];
#pragma unroll
        for (int k = 0; k < 8; ++k) {
            float R = Rv[k], G = Gv[k], B = Bv[k];
            if (ch == 0)      g[k] = 0.299f * R + 0.587f * G + 0.114f * B - 0.5f;
            else if (ch == 1) g[k] = -0.168736f * R - 0.331264f * G + 0.5f * B;
            else              g[k] = 0.5f * R - 0.418688f * G - 0.081312f * B;
        }

        // ---- horizontal DCT (over y, in-lane) ----
        fdct8(g);   // g[v] = coefH[x=row][v]  for block blk

        // ---- transpose 1: (x, v) -> lane holds fixed v, all x ----
#pragma unroll
        for (int v = 0; v < 8; ++v) xp[v * 72 + blk * 9 + row] = g[v];
        float w[8];
#pragma unroll
        for (int k = 0; k < 8; ++k) w[k] = xp[row * 72 + blk * 9 + k];
        // now: lane's `row` plays freq v; w[x'] = coefH[x'][v]

        // ---- vertical DCT (over x, in-lane) ----
        fdct8(w);   // w[u] = coef[u][v]

        // ---- soft quantize-dequantize; q indexed [v*8+u], v = row ----
        {
            const float* qrow = &qt[ch ? 1 : 0][row * 8];
            float q[8], rq[8];
#pragma unroll
            for (int u = 0; u < 8; ++u) { q[u] = qrow[u]; rq[u] = __builtin_amdgcn_rcpf(q[u]); }
#pragma unroll
            for (int u = 0; u < 8; ++u) w[u] = softq(w[u], q[u], rq[u]);
        }

        // ---- vertical inverse DCT (over u, in-lane) ----
        idct8(w);   // w[x'] = partial[x'][v]

        // ---- transpose 2 (mirror addressing of transpose 1) ----
#pragma unroll
        for (int k = 0; k < 8; ++k) xp[row * 72 + blk * 9 + k] = w[k];
        float r[8];
#pragma unroll
        for (int v = 0; v < 8; ++v) r[v] = xp[v * 72 + blk * 9 + row];
        // lane (blk,row): r[v] = partial[x=row][v]

        // ---- horizontal inverse DCT -> reconstructed spatial row ----
        idct8(r);
#pragma unroll
        for (int k = 0; k < 8; ++k) rec[ch][k] = r[k];
    }

    // ---- inverse color + coalesced stores ----
    f8v Ro, Go, Bo;
#pragma unroll
    for (int k = 0; k < 8; ++k) {
        float Y  = rec[0][k] + 0.5f;
        float Cb = rec[1][k];
        float Cr = rec[2][k];
        float R = Y + 1.402f * Cr;
        float G = Y - 0.344136f * Cb - 0.714136f * Cr;
        float B = Y + 1.772f * Cb;
        Ro[k] = fminf(fmaxf(R, 0.0f), 1.0f);
        Go[k] = fminf(fmaxf(G, 0.0f), 1.0f);
        Bo[k] = fminf(fmaxf(B, 0.0f), 1.0f);
    }
    *(f8v*)(obase) = Ro;
    *(f8v*)(obase + IMG_HW) = Go;
    *(f8v*)(obase + 2 * IMG_HW) = Bo;
}

extern "C" void kernel_launch(void* const* d_in, const int* in_sizes, int n_in,
                              void* d_out, int out_size, void* d_ws, size_t ws_size,
                              hipStream_t stream) {
    const float* x = (const float*)d_in[0];
    float* out = (float*)d_out;
    const int B = in_sizes[0] / (3 * IMG_HW);        // 32
    const int n_wg = B * 128;                        // B*512 waves / 4 per WG
    hipLaunchKernelGGL(jpeg_kernel, dim3(n_wg), dim3(256), 0, stream, x, out);
}